// Round 8
// baseline (197.484 us; speedup 1.0000x reference)
//
#include <hip/hip_runtime.h>

#define N_NODES 100000
#define N_EDGES 1600000
#define D 128
#define SLOT_CAP 64
#define TILE 32            // nodes per gather block (100000 = 3125 * 32)

// fused_pre geometry: fill blocks FIRST (latency-bound, wants clean L2),
// conv blocks after.
#define NR           8                   // dst ranges == XCDs
#define RANGE_N      (N_NODES / NR)      // 12500
#define CHUNK4       512                 // int4 per chunk = 2048 edges
#define NCHUNK       ((N_EDGES / 4 + CHUNK4 - 1) / CHUNK4)   // 782
#define FILL_BLOCKS  (NR * NCHUNK)       // 6256
#define FEAT4        (N_NODES * D / 4)   // 3,200,000 float4 -> uint2
#define CONVF_BASE   FILL_BLOCKS
#define CONVF_BLOCKS 12500
#define CONVW_BASE   (CONVF_BASE + CONVF_BLOCKS)
#define TOTAL_BLOCKS (CONVW_BASE + 16)

typedef __attribute__((ext_vector_type(8))) short bf16x8;
typedef __attribute__((ext_vector_type(4))) float f32x4;
// ext_vector aliases usable with __builtin_nontemporal_*
typedef __attribute__((ext_vector_type(4))) float evf4;
typedef __attribute__((ext_vector_type(4))) int   evi4;
typedef __attribute__((ext_vector_type(2))) unsigned int evu2;
typedef __attribute__((ext_vector_type(4))) unsigned int evu4;

static __device__ __forceinline__ evf4 nt_load_f4(const void* p) {
    return __builtin_nontemporal_load((const evf4*)p);
}
static __device__ __forceinline__ evi4 nt_load_i4(const void* p) {
    return __builtin_nontemporal_load((const evi4*)p);
}
static __device__ __forceinline__ int nt_load_i(const int* p) {
    return __builtin_nontemporal_load(p);
}
static __device__ __forceinline__ float nt_load_f(const float* p) {
    return __builtin_nontemporal_load(p);
}
static __device__ __forceinline__ void nt_store_u2(void* p, evu2 v) {
    __builtin_nontemporal_store(v, (evu2*)p);
}
static __device__ __forceinline__ void nt_store_f4(void* p, evf4 v) {
    __builtin_nontemporal_store(v, (evf4*)p);
}

static __device__ __forceinline__ unsigned int f2bf(float f) {
    union { float f; unsigned int u; } v; v.f = f;
    return (v.u + 0x7FFFu + ((v.u >> 16) & 1u)) >> 16;   // RNE
}
static __device__ __forceinline__ float bflo(unsigned int u) {
    return __uint_as_float(u << 16);
}
static __device__ __forceinline__ float bfhi(unsigned int u) {
    return __uint_as_float(u & 0xFFFF0000u);
}

// ---------------------------------------------------------------------------
// Fused pre-pass. All streaming traffic is non-temporal so each XCD's L2
// holds ONLY its partition's cnt+slot lines -> scattered 4B slot entries
// write-combine (~16 entries / 64B line).
//   blocks [0, FILL_BLOCKS): XCD-range-partitioned fill. Loads dst4 (nt),
//     fetches src/w per-element only when in range (1/8 of edges).
//   blocks [CONVF_BASE, +12500): feature f32 -> bf16 (nt in, nt out)
//   blocks [CONVW_BASE, +16): W f32 -> bf16
// Slot entry packed to 4B: (src << 15) | trunc(w * 32768).
// ---------------------------------------------------------------------------
__global__ __launch_bounds__(256) void fused_pre(const float* __restrict__ feat,
                                                 const float* __restrict__ W,
                                                 unsigned int* __restrict__ fbf2,
                                                 unsigned int* __restrict__ Wbf2,
                                                 const int* __restrict__ src,
                                                 const int* __restrict__ dst,
                                                 const float* __restrict__ w,
                                                 int* __restrict__ cnt,
                                                 int* __restrict__ slots) {
    const int b = blockIdx.x;
    const int tid = threadIdx.x;

    if (b < FILL_BLOCKS) {
        const unsigned r = b & (NR - 1);
        const int chunk = b >> 3;
        const unsigned rlo = r * RANGE_N;
        const int base4 = chunk * CHUNK4;

#pragma unroll
        for (int j = 0; j < 2; ++j) {
            int i4 = base4 + j * 256 + tid;
            if (i4 < N_EDGES / 4) {
                evi4 dd = nt_load_i4(dst + i4 * 4);
#define PROCE(K)                                                              \
                {   int dc = dd[K];                                           \
                    if ((unsigned)(dc - rlo) < (unsigned)RANGE_N) {           \
                        int   sc = nt_load_i(src + i4 * 4 + (K));             \
                        float wc = nt_load_f(w + i4 * 4 + (K));               \
                        int p = atomicAdd(&cnt[dc], 1);                       \
                        if (p < SLOT_CAP)                                     \
                            slots[dc * SLOT_CAP + p] =                        \
                                (sc << 15) | (int)(wc * 32768.0f);            \
                    }                                                         \
                }
                PROCE(0)
                PROCE(1)
                PROCE(2)
                PROCE(3)
#undef PROCE
            }
        }
        return;
    }

    if (b < CONVW_BASE) {                         // feature -> bf16
        int i = (b - CONVF_BASE) * 256 + tid;
        if (i < FEAT4) {
            evf4 v = nt_load_f4(feat + i * 4);
            evu2 o;
            o.x = f2bf(v.x) | (f2bf(v.y) << 16);
            o.y = f2bf(v.z) | (f2bf(v.w) << 16);
            nt_store_u2(fbf2 + i * 2, o);
        }
        return;
    }

    {                                             // W -> bf16 (4096 float4)
        int i = (b - CONVW_BASE) * 256 + tid;
        if (i < 4096) {
            evf4 v = nt_load_f4(W + i * 4);
            evu2 o;
            o.x = f2bf(v.x) | (f2bf(v.y) << 16);
            o.y = f2bf(v.z) | (f2bf(v.w) << 16);
            nt_store_u2(Wbf2 + i * 2, o);
        }
    }
}

// ---------------------------------------------------------------------------
// Fused gather + GEMM per 32-node tile, 4 waves.
// Phase 1: depth-4 pipelined gather (quarter-wave g owns edge i+g; 4 row
//   loads in flight per wave). Single-use streams (cnt, slots) non-temporal;
//   fbf rows temporal (L2 reuse across edges).
// Phase 2: 16x16x32 bf16 MFMA, A from XOR-swizzled LDS h-tile, B from global.
// Phase 3: C+bias staged in LDS, coalesced non-temporal float4 store.
// ---------------------------------------------------------------------------
__global__ __launch_bounds__(256) void gather_gemm(const int* __restrict__ cnt,
                                                   const int* __restrict__ slots,
                                                   const unsigned short* __restrict__ fbf,
                                                   const unsigned short* __restrict__ Wbf,
                                                   const float* __restrict__ bias,
                                                   float* __restrict__ y) {
    __shared__ char smem[TILE * D * 4];        // 16 KB: h (8 KB bf16) then C (16 KB f32)
    char*  hT = smem;
    float* C  = (float*)smem;

    const int tid   = threadIdx.x;
    const int wave  = tid >> 6;
    const int lane  = tid & 63;
    const int vbase = blockIdx.x * TILE;
    const int g  = lane >> 4;                  // quarter-wave group 0..3
    const int ql = lane & 15;
    const uint4* fbf4 = (const uint4*)fbf;     // 16 uint4 per 128-col row

    // ---- Phase 1: gather h rows ----
    for (int n = 0; n < 8; ++n) {
        const int row = wave * 8 + n;
        const int v = vbase + row;
        int c = nt_load_i(cnt + v);
        c = c < SLOT_CAP ? c : SLOT_CAP;
        int ent = (lane < c) ? nt_load_i(slots + v * SLOT_CAP + lane) : 0;

        float acc[8];
#pragma unroll
        for (int j = 0; j < 8; ++j) acc[j] = 0.f;

#define FETCH(P, W, I)                                                        \
        {   int pe = __shfl(ent, (I) + g);                                    \
            W = (float)(pe & 32767) * (1.0f / 32768.0f);                      \
            int s = ((unsigned)pe) >> 15;                                     \
            P = fbf4[(long long)s * 16 + ql]; }
#define PROC(P, W)                                                            \
        {   acc[0] += W * bflo(P.x); acc[1] += W * bfhi(P.x);                 \
            acc[2] += W * bflo(P.y); acc[3] += W * bfhi(P.y);                 \
            acc[4] += W * bflo(P.z); acc[5] += W * bfhi(P.z);                 \
            acc[6] += W * bflo(P.w); acc[7] += W * bfhi(P.w); }

        if (c > 0) {
            const int c16 = (c + 15) & ~15;    // pad to x16 (dummies: w=0,row 0)
            uint4 p0, p1, p2, p3;
            float w0, w1, w2, w3;
            FETCH(p0, w0, 0) FETCH(p1, w1, 4) FETCH(p2, w2, 8) FETCH(p3, w3, 12)
            for (int i = 0; i < c16; i += 16) {
                PROC(p0, w0) if (i + 16 < c16) FETCH(p0, w0, i + 16)
                PROC(p1, w1) if (i + 20 < c16) FETCH(p1, w1, i + 20)
                PROC(p2, w2) if (i + 24 < c16) FETCH(p2, w2, i + 24)
                PROC(p3, w3) if (i + 28 < c16) FETCH(p3, w3, i + 28)
            }
        }
#undef FETCH
#undef PROC

#pragma unroll
        for (int j = 0; j < 8; ++j) {
            acc[j] += __shfl_xor(acc[j], 16);
            acc[j] += __shfl_xor(acc[j], 32);
        }
        if (lane < 16) {
            uint4 pk;
            pk.x = f2bf(acc[0]) | (f2bf(acc[1]) << 16);
            pk.y = f2bf(acc[2]) | (f2bf(acc[3]) << 16);
            pk.z = f2bf(acc[4]) | (f2bf(acc[5]) << 16);
            pk.w = f2bf(acc[6]) | (f2bf(acc[7]) << 16);
            int cb = (lane * 16) ^ ((row & 7) << 4);
            *(uint4*)(hT + row * 256 + cb) = pk;
        }
    }
    __syncthreads();

    // ---- Phase 2: load A-frags from LDS, then MFMA with B from global ----
    const int m0  = (wave & 1) * 16;
    const int n0  = (wave >> 1) * 64;
    const int lr  = lane & 15;
    const int lkb = (lane >> 4) * 16;          // k byte offset within 256B row
    const int lk  = (lane >> 4) * 8;           // k element offset
    const int arow = m0 + lr;

    bf16x8 a[4];
#pragma unroll
    for (int t = 0; t < 4; ++t) {
        int cb = (t * 64 + lkb) ^ ((arow & 7) << 4);
        a[t] = *(const bf16x8*)(hT + arow * 256 + cb);
    }
    __syncthreads();                           // frags in regs; smem now reusable as C

    f32x4 acc2[4];
#pragma unroll
    for (int ni = 0; ni < 4; ++ni) acc2[ni] = (f32x4){0.f, 0.f, 0.f, 0.f};
#pragma unroll
    for (int t = 0; t < 4; ++t) {
#pragma unroll
        for (int ni = 0; ni < 4; ++ni) {
            bf16x8 b = *(const bf16x8*)(Wbf + (n0 + ni * 16 + lr) * D + t * 32 + lk);
            acc2[ni] = __builtin_amdgcn_mfma_f32_16x16x32_bf16(a[t], b, acc2[ni], 0, 0, 0);
        }
    }

    // ---- Phase 3: C+bias -> LDS, coalesced store ----
#pragma unroll
    for (int ni = 0; ni < 4; ++ni) {
        float bv = bias[n0 + ni * 16 + lr];
#pragma unroll
        for (int r = 0; r < 4; ++r) {
            int row = m0 + (lane >> 4) * 4 + r;
            C[row * D + n0 + ni * 16 + lr] = acc2[ni][r] + bv;
        }
    }
    __syncthreads();

    float* yb = y + (long long)vbase * D;
    const evf4* C4 = (const evf4*)C;
#pragma unroll
    for (int rep = 0; rep < 4; ++rep)
        nt_store_f4(yb + (rep * 256 + tid) * 4, C4[rep * 256 + tid]);
}

extern "C" void kernel_launch(void* const* d_in, const int* in_sizes, int n_in,
                              void* d_out, int out_size, void* d_ws, size_t ws_size,
                              hipStream_t stream) {
    const float* feature = (const float*)d_in[0];
    const int*   src     = (const int*)d_in[1];
    const int*   dst     = (const int*)d_in[2];
    const float* ew      = (const float*)d_in[3];
    const float* W       = (const float*)d_in[4];
    const float* b       = (const float*)d_in[5];
    float* y = (float*)d_out;

    char* ws = (char*)d_ws;
    unsigned short* fbf   = (unsigned short*)(ws);                // 25,600,000 B
    int*            cnt   = (int*)(ws + 25600000);                //    400,000 B
    int*            slots = (int*)(ws + 26000000);                // 25,600,000 B (4B packed)
    unsigned short* Wbf   = (unsigned short*)(ws + 77200000);     //     32,768 B

    hipMemsetAsync(cnt, 0, 400000, stream);

    fused_pre<<<TOTAL_BLOCKS, 256, 0, stream>>>(
        feature, W,
        (unsigned int*)fbf, (unsigned int*)Wbf,
        src, dst, ew,
        cnt, slots);

    gather_gemm<<<N_NODES / TILE, 256, 0, stream>>>(cnt, slots, fbf, Wbf, b, y);
}

// Round 9
// 170.705 us; speedup vs baseline: 1.1569x; 1.1569x over previous
//
#include <hip/hip_runtime.h>

#define N_NODES 100000
#define N_EDGES 1600000
#define D 128
#define SLOT_CAP 64
#define TILE 32            // nodes per gather block (100000 = 3125 * 32)

// fused_pre geometry (round-6 known-good: 89 us)
#define NR           8                   // dst ranges == XCDs
#define RANGE_N      (N_NODES / NR)      // 12500
#define CHUNK4       512                 // int4 per chunk = 2048 edges
#define NCHUNK       ((N_EDGES / 4 + CHUNK4 - 1) / CHUNK4)   // 782
#define FILL_BLOCKS  (NR * NCHUNK)       // 6256
#define FEAT4        (N_NODES * D / 4)   // 3,200,000 float4 -> uint2
#define CONVF_BASE   FILL_BLOCKS
#define CONVF_BLOCKS 12500
#define CONVW_BASE   (CONVF_BASE + CONVF_BLOCKS)
#define TOTAL_BLOCKS (CONVW_BASE + 16)

typedef __attribute__((ext_vector_type(8))) short bf16x8;
typedef __attribute__((ext_vector_type(4))) float f32x4;

static __device__ __forceinline__ unsigned int f2bf(float f) {
    union { float f; unsigned int u; } v; v.f = f;
    return (v.u + 0x7FFFu + ((v.u >> 16) & 1u)) >> 16;   // RNE
}
static __device__ __forceinline__ float bflo(unsigned int u) {
    return __uint_as_float(u << 16);
}
static __device__ __forceinline__ float bfhi(unsigned int u) {
    return __uint_as_float(u & 0xFFFF0000u);
}

// ---------------------------------------------------------------------------
// Fused pre-pass (round-6 version, temporal loads).
//   blocks [0, FILL_BLOCKS): XCD-range-partitioned fill (range = b & 7).
//   blocks [CONVF_BASE, +12500): feature f32 -> bf16
//   blocks [CONVW_BASE, +16): W f32 -> bf16
// Slot entry packed to 4B: (src << 15) | trunc(w * 32768).
// ---------------------------------------------------------------------------
__global__ __launch_bounds__(256) void fused_pre(const float4* __restrict__ feat4,
                                                 const float4* __restrict__ W4,
                                                 uint2* __restrict__ fbf2,
                                                 uint2* __restrict__ Wbf2,
                                                 const int* __restrict__ src,
                                                 const int4* __restrict__ dst4,
                                                 const float* __restrict__ w,
                                                 int* __restrict__ cnt,
                                                 int* __restrict__ slots) {
    const int b = blockIdx.x;
    const int tid = threadIdx.x;

    if (b < FILL_BLOCKS) {
        const unsigned r = b & (NR - 1);
        const int chunk = b >> 3;
        const unsigned rlo = r * RANGE_N;
        const int base4 = chunk * CHUNK4;

#pragma unroll
        for (int j = 0; j < 2; ++j) {
            int i4 = base4 + j * 256 + tid;
            if (i4 < N_EDGES / 4) {
                int4 dd = dst4[i4];
#define PROCE(K, dc)                                                          \
                if ((unsigned)((dc) - rlo) < (unsigned)RANGE_N) {             \
                    int   sc = src[i4 * 4 + (K)];                             \
                    float wc = w[i4 * 4 + (K)];                               \
                    int p = atomicAdd(&cnt[dc], 1);                           \
                    if (p < SLOT_CAP)                                         \
                        slots[(dc) * SLOT_CAP + p] =                          \
                            (sc << 15) | (int)(wc * 32768.0f);                \
                }
                PROCE(0, dd.x)
                PROCE(1, dd.y)
                PROCE(2, dd.z)
                PROCE(3, dd.w)
#undef PROCE
            }
        }
        return;
    }

    if (b < CONVW_BASE) {                         // feature -> bf16
        int i = (b - CONVF_BASE) * 256 + tid;
        if (i < FEAT4) {
            float4 v = feat4[i];
            uint2 o;
            o.x = f2bf(v.x) | (f2bf(v.y) << 16);
            o.y = f2bf(v.z) | (f2bf(v.w) << 16);
            fbf2[i] = o;
        }
        return;
    }

    {                                             // W -> bf16 (4096 float4)
        int i = (b - CONVW_BASE) * 256 + tid;
        if (i < 4096) {
            float4 v = W4[i];
            uint2 o;
            o.x = f2bf(v.x) | (f2bf(v.y) << 16);
            o.y = f2bf(v.z) | (f2bf(v.w) << 16);
            Wbf2[i] = o;
        }
    }
}

// ---------------------------------------------------------------------------
// Fused gather + GEMM per 32-node tile, 4 waves.
// Phase 1: TWO rows interleaved per wave (pairs), depth-4 pipeline per row
//   -> 32 edges in flight per wave; next pair's ent prefetched during
//   current pair's compute; cnt loaded once lane-parallel.
// Phase 2: 16x16x32 bf16 MFMA, A from XOR-swizzled LDS h-tile, B from global.
// Phase 3: C+bias staged in LDS, coalesced float4 store.
// ---------------------------------------------------------------------------
__global__ __launch_bounds__(256) void gather_gemm(const int* __restrict__ cnt,
                                                   const int* __restrict__ slots,
                                                   const unsigned short* __restrict__ fbf,
                                                   const unsigned short* __restrict__ Wbf,
                                                   const float* __restrict__ bias,
                                                   float* __restrict__ y) {
    __shared__ char smem[TILE * D * 4];        // 16 KB: h (8 KB bf16) then C (16 KB f32)
    char*  hT = smem;
    float* C  = (float*)smem;

    const int tid   = threadIdx.x;
    const int wave  = tid >> 6;
    const int lane  = tid & 63;
    const int vbase = blockIdx.x * TILE;
    const int g  = lane >> 4;                  // quarter-wave group 0..3
    const int ql = lane & 15;
    const uint4* fbf4 = (const uint4*)fbf;     // 16 uint4 per 128-col row

    // ---- Phase 1: gather h rows (pairs of rows, pipelined) ----
    const int rbase = wave * 8;
    const int vA0 = vbase + rbase;

    int cAll = (lane < 8) ? cnt[vA0 + lane] : 0;

    int entA = 0, entB = 0;
    {
        int ca = __shfl(cAll, 0);
        int cb = __shfl(cAll, 1);
        if (lane < ca) entA = slots[(vA0 + 0) * SLOT_CAP + lane];
        if (lane < cb) entB = slots[(vA0 + 1) * SLOT_CAP + lane];
    }

#define FETCHX(ENT, P, W, I)                                                  \
    {   int pe = __shfl(ENT, (I) + g);                                        \
        W = (float)(pe & 32767) * (1.0f / 32768.0f);                          \
        int s = ((unsigned)pe) >> 15;                                         \
        P = fbf4[(long long)s * 16 + ql]; }
#define PROCX(P, W, ACC)                                                      \
    {   ACC[0] += W * bflo(P.x); ACC[1] += W * bfhi(P.x);                     \
        ACC[2] += W * bflo(P.y); ACC[3] += W * bfhi(P.y);                     \
        ACC[4] += W * bflo(P.z); ACC[5] += W * bfhi(P.z);                     \
        ACC[6] += W * bflo(P.w); ACC[7] += W * bfhi(P.w); }

    for (int p = 0; p < 4; ++p) {
        int cA = __shfl(cAll, 2 * p);     cA = cA < SLOT_CAP ? cA : SLOT_CAP;
        int cB = __shfl(cAll, 2 * p + 1); cB = cB < SLOT_CAP ? cB : SLOT_CAP;
        int c16A = (cA + 15) & ~15; c16A = c16A < 16 ? 16 : c16A;  // >=1 iter (dummies w=0)
        int c16B = (cB + 15) & ~15; c16B = c16B < 16 ? 16 : c16B;

        float accA[8], accB[8];
#pragma unroll
        for (int j = 0; j < 8; ++j) { accA[j] = 0.f; accB[j] = 0.f; }

        uint4 pA0, pA1, pA2, pA3, pB0, pB1, pB2, pB3;
        float wA0, wA1, wA2, wA3, wB0, wB1, wB2, wB3;
        FETCHX(entA, pA0, wA0, 0)  FETCHX(entB, pB0, wB0, 0)
        FETCHX(entA, pA1, wA1, 4)  FETCHX(entB, pB1, wB1, 4)
        FETCHX(entA, pA2, wA2, 8)  FETCHX(entB, pB2, wB2, 8)
        FETCHX(entA, pA3, wA3, 12) FETCHX(entB, pB3, wB3, 12)

        // prefetch next pair's ents while this pair computes
        int entAn = 0, entBn = 0;
        if (p < 3) {
            int ca = __shfl(cAll, 2 * p + 2);
            int cb = __shfl(cAll, 2 * p + 3);
            if (lane < ca) entAn = slots[(vA0 + 2 * p + 2) * SLOT_CAP + lane];
            if (lane < cb) entBn = slots[(vA0 + 2 * p + 3) * SLOT_CAP + lane];
        }

        const int imax = c16A > c16B ? c16A : c16B;
        for (int i = 0; i < imax; i += 16) {
            if (i < c16A) {
                PROCX(pA0, wA0, accA) if (i + 16 < c16A) FETCHX(entA, pA0, wA0, i + 16)
                PROCX(pA1, wA1, accA) if (i + 20 < c16A) FETCHX(entA, pA1, wA1, i + 20)
                PROCX(pA2, wA2, accA) if (i + 24 < c16A) FETCHX(entA, pA2, wA2, i + 24)
                PROCX(pA3, wA3, accA) if (i + 28 < c16A) FETCHX(entA, pA3, wA3, i + 28)
            }
            if (i < c16B) {
                PROCX(pB0, wB0, accB) if (i + 16 < c16B) FETCHX(entB, pB0, wB0, i + 16)
                PROCX(pB1, wB1, accB) if (i + 20 < c16B) FETCHX(entB, pB1, wB1, i + 20)
                PROCX(pB2, wB2, accB) if (i + 24 < c16B) FETCHX(entB, pB2, wB2, i + 24)
                PROCX(pB3, wB3, accB) if (i + 28 < c16B) FETCHX(entB, pB3, wB3, i + 28)
            }
        }
#undef FETCHX
#undef PROCX

#pragma unroll
        for (int j = 0; j < 8; ++j) {
            accA[j] += __shfl_xor(accA[j], 16);
            accA[j] += __shfl_xor(accA[j], 32);
            accB[j] += __shfl_xor(accB[j], 16);
            accB[j] += __shfl_xor(accB[j], 32);
        }
        if (lane < 16) {
            const int rowA = rbase + 2 * p;
            uint4 pk;
            pk.x = f2bf(accA[0]) | (f2bf(accA[1]) << 16);
            pk.y = f2bf(accA[2]) | (f2bf(accA[3]) << 16);
            pk.z = f2bf(accA[4]) | (f2bf(accA[5]) << 16);
            pk.w = f2bf(accA[6]) | (f2bf(accA[7]) << 16);
            int cb1 = (lane * 16) ^ ((rowA & 7) << 4);
            *(uint4*)(hT + rowA * 256 + cb1) = pk;
            const int rowB = rowA + 1;
            pk.x = f2bf(accB[0]) | (f2bf(accB[1]) << 16);
            pk.y = f2bf(accB[2]) | (f2bf(accB[3]) << 16);
            pk.z = f2bf(accB[4]) | (f2bf(accB[5]) << 16);
            pk.w = f2bf(accB[6]) | (f2bf(accB[7]) << 16);
            int cb2 = (lane * 16) ^ ((rowB & 7) << 4);
            *(uint4*)(hT + rowB * 256 + cb2) = pk;
        }
        entA = entAn;
        entB = entBn;
    }
    __syncthreads();

    // ---- Phase 2: load A-frags from LDS, then MFMA with B from global ----
    const int m0  = (wave & 1) * 16;
    const int n0  = (wave >> 1) * 64;
    const int lr  = lane & 15;
    const int lkb = (lane >> 4) * 16;          // k byte offset within 256B row
    const int lk  = (lane >> 4) * 8;           // k element offset
    const int arow = m0 + lr;

    bf16x8 a[4];
#pragma unroll
    for (int t = 0; t < 4; ++t) {
        int cb = (t * 64 + lkb) ^ ((arow & 7) << 4);
        a[t] = *(const bf16x8*)(hT + arow * 256 + cb);
    }
    __syncthreads();                           // frags in regs; smem now reusable as C

    f32x4 acc2[4];
#pragma unroll
    for (int ni = 0; ni < 4; ++ni) acc2[ni] = (f32x4){0.f, 0.f, 0.f, 0.f};
#pragma unroll
    for (int t = 0; t < 4; ++t) {
#pragma unroll
        for (int ni = 0; ni < 4; ++ni) {
            bf16x8 b = *(const bf16x8*)(Wbf + (n0 + ni * 16 + lr) * D + t * 32 + lk);
            acc2[ni] = __builtin_amdgcn_mfma_f32_16x16x32_bf16(a[t], b, acc2[ni], 0, 0, 0);
        }
    }

    // ---- Phase 3: C+bias -> LDS, coalesced store ----
#pragma unroll
    for (int ni = 0; ni < 4; ++ni) {
        float bv = bias[n0 + ni * 16 + lr];
#pragma unroll
        for (int r = 0; r < 4; ++r) {
            int row = m0 + (lane >> 4) * 4 + r;
            C[row * D + n0 + ni * 16 + lr] = acc2[ni][r] + bv;
        }
    }
    __syncthreads();

    float4* y4 = (float4*)(y + (long long)vbase * D);
    const float4* C4 = (const float4*)C;
#pragma unroll
    for (int rep = 0; rep < 4; ++rep)
        y4[rep * 256 + tid] = C4[rep * 256 + tid];
}

extern "C" void kernel_launch(void* const* d_in, const int* in_sizes, int n_in,
                              void* d_out, int out_size, void* d_ws, size_t ws_size,
                              hipStream_t stream) {
    const float* feature = (const float*)d_in[0];
    const int*   src     = (const int*)d_in[1];
    const int*   dst     = (const int*)d_in[2];
    const float* ew      = (const float*)d_in[3];
    const float* W       = (const float*)d_in[4];
    const float* b       = (const float*)d_in[5];
    float* y = (float*)d_out;

    char* ws = (char*)d_ws;
    unsigned short* fbf   = (unsigned short*)(ws);                // 25,600,000 B
    int*            cnt   = (int*)(ws + 25600000);                //    400,000 B
    int*            slots = (int*)(ws + 26000000);                // 25,600,000 B (4B packed)
    unsigned short* Wbf   = (unsigned short*)(ws + 77200000);     //     32,768 B

    hipMemsetAsync(cnt, 0, 400000, stream);

    fused_pre<<<TOTAL_BLOCKS, 256, 0, stream>>>(
        (const float4*)feature, (const float4*)W,
        (uint2*)fbf, (uint2*)Wbf,
        src, (const int4*)dst, ew,
        cnt, slots);

    gather_gemm<<<N_NODES / TILE, 256, 0, stream>>>(cnt, slots, fbf, Wbf, b, y);
}